// Round 3
// baseline (194.701 us; speedup 1.0000x reference)
//
#include <hip/hip_runtime.h>
#include <hip/hip_bf16.h>
#include <math.h>

// Problem constants (B=16, L=256, D=256, K=16384)
#define NROWS 4096               // B*L anchors / z rows
#define KMEM  16384
#define NCAND 20480              // NROWS + KMEM candidates
#define DIM   256                // feature dim
#define TM    64                 // anchor rows per block (A-LDS resident, full K)
#define NSLICE 16                // candidate column slices (grid.y)
#define COLS_PER_SLICE (NCAND / NSLICE)       // 1280
#define TILE_COLS 256            // cols per t-iteration (4 waves x 64)
#define TILES_PER_SLICE (COLS_PER_SLICE / TILE_COLS)  // 5
#define INV_T  (1.0f / 0.07f)
#define SCALE2 (1.4426950408889634f / 0.07f)  // log2(e)/T, folded in epilogue
#define LN2    0.6931471805599453f

typedef short  short8 __attribute__((ext_vector_type(8)));  // 8 bf16 (4 VGPRs)
typedef float  f32x4  __attribute__((ext_vector_type(4)));  // MFMA C/D
typedef unsigned short ushort_t;

// RNE float->bf16 (inputs are finite normals; no NaN path needed)
__device__ inline ushort_t f2bf(float x) {
    union { float f; unsigned u; } a; a.f = x;
    unsigned r = a.u + 0x7fff + ((a.u >> 16) & 1);
    return (ushort_t)(r >> 16);
}

// async global->LDS, 16B per lane, dest = wave-uniform base + lane*16
__device__ inline void load_lds16(const void* g, void* l) {
    __builtin_amdgcn_global_load_lds(
        (const __attribute__((address_space(1))) unsigned int*)g,
        (__attribute__((address_space(3))) unsigned int*)l, 16, 0, 0);
}

// Kernel 0: cast fp32 -> bf16 into cand = [z ; mem] (single array, unscaled).
__global__ __launch_bounds__(256) void cast_kernel(
    const float* __restrict__ z, const float* __restrict__ mem,
    ushort_t* __restrict__ cand)
{
    const int idx = blockIdx.x * 256 + threadIdx.x;  // float4 index, < 1310720
    const int ZQ = NROWS * DIM / 4;                  // 262144
    const float4 v = (idx < ZQ) ? ((const float4*)z)[idx]
                                : ((const float4*)mem)[idx - ZQ];
    ushort4 u; u.x = f2bf(v.x); u.y = f2bf(v.y); u.z = f2bf(v.z); u.w = f2bf(v.w);
    ((ushort4*)cand)[idx] = u;
}

// Kernel A: barrier-free MFMA flash-LSE.
// Block = 4 waves side-by-side (wave w owns 64 cols of a 256-col tile),
// TM=64 anchor rows. A (64x256 bf16 = 32KB) staged into LDS ONCE at start
// (XOR 16B-chunk swizzle -> fragment ds_read_b128 at 2-way alias = free).
// B fragments are read DIRECTLY from global (16B contiguous in k, L2-served)
// -- no B staging, no __syncthreads in the entire tile/K loop, so waves
// slip freely and the compiler pipelines global loads against MFMA groups.
// Online-softmax state per lane in base-2; log2(e)/T folded via fma.
__global__ __launch_bounds__(256) void mfma_lse_kernel(
    const ushort_t* __restrict__ zb, const ushort_t* __restrict__ cand,
    float* __restrict__ part_m, float* __restrict__ part_s)
{
    __shared__ __align__(16) ushort_t ldsA[TM * DIM];   // 32 KB

    const int tid  = threadIdx.x;
    const int lane = tid & 63;
    const int w    = tid >> 6;        // wave 0..3 (column quarter)
    const int quad = lane >> 4;
    const int ln   = lane & 15;
    const int rowBase = blockIdx.x * TM;
    const int slice   = blockIdx.y;

    // --- Stage A once: wave w loads rows [w*16, w*16+16), 8 instrs x 2 rows.
    // Lane l -> row += l/32, chunk position p = l%32 holds global chunk
    // c = p ^ (row&7)  (XOR swizzle; reading chunk c later uses p = c^(row&7)).
#pragma unroll
    for (int u = 0; u < 8; ++u) {
        const int row = w * 16 + u * 2 + (lane >> 5);
        const int c   = (lane & 31) ^ (row & 7);
        load_lds16(zb + (size_t)(rowBase + row) * DIM + c * 8,
                   ldsA + (w * 16 + u * 2) * DIM);
    }
    __syncthreads();   // the only barrier before the final merge

    float m2[16], s[16];
#pragma unroll
    for (int i = 0; i < 16; ++i) { m2[i] = -INFINITY; s[i] = 0.0f; }

    for (int t = 0; t < TILES_PER_SLICE; ++t) {
        const int colW = slice * COLS_PER_SLICE + t * TILE_COLS + w * 64;
        f32x4 acc[4][4];
#pragma unroll
        for (int ti = 0; ti < 4; ++ti)
#pragma unroll
            for (int tj = 0; tj < 4; ++tj) acc[ti][tj] = (f32x4)0.0f;

        // B fragment base for this wave: col = colW + tj*16 + ln, k = ks*32+quad*8
        const ushort_t* bp = cand + (size_t)(colW + ln) * DIM + quad * 8;

#pragma unroll
        for (int ks = 0; ks < DIM / 32; ++ks) {
            short8 af[4], bfr[4];
#pragma unroll
            for (int ti = 0; ti < 4; ++ti) {
                const int row = ti * 16 + ln;
                const int p   = (ks * 4 + quad) ^ (ln & 7);   // swizzled chunk pos
                af[ti] = *(const short8*)(ldsA + row * DIM + p * 8);
            }
#pragma unroll
            for (int tj = 0; tj < 4; ++tj)
                bfr[tj] = *(const short8*)(bp + tj * 16 * DIM + ks * 32);
#pragma unroll
            for (int ti = 0; ti < 4; ++ti)
#pragma unroll
                for (int tj = 0; tj < 4; ++tj)
                    acc[ti][tj] = __builtin_amdgcn_mfma_f32_16x16x32_bf16(
                        af[ti], bfr[tj], acc[ti][tj], 0, 0, 0);
        }

        // Epilogue: base-2 online update; scale folded via fma. Per-lane only.
        // C/D layout: col = ln + 16*tj (+colW), row = quad*4 + reg (+16*ti)
        const bool hasDiag = (colW < rowBase + TM) && (rowBase < colW + 64);
#pragma unroll
        for (int ti = 0; ti < 4; ++ti) {
#pragma unroll
            for (int r = 0; r < 4; ++r) {
                const int idx = ti * 4 + r;
                float v0 = acc[ti][0][r], v1 = acc[ti][1][r];
                float v2 = acc[ti][2][r], v3 = acc[ti][3][r];
                if (hasDiag) {
                    const int grow = rowBase + ti * 16 + quad * 4 + r;
                    const int gc0  = colW + ln;
                    if (gc0      == grow) v0 = -3.0e38f;   // mask self-sim
                    if (gc0 + 16 == grow) v1 = -3.0e38f;
                    if (gc0 + 32 == grow) v2 = -3.0e38f;
                    if (gc0 + 48 == grow) v3 = -3.0e38f;
                }
                const float tmax = fmaxf(fmaxf(v0, v1), fmaxf(v2, v3)) * SCALE2;
                const float mo = m2[idx];
                const float mn = fmaxf(mo, tmax);
                const float sc = __builtin_amdgcn_exp2f(mo - mn);  // exp2(-inf)=0
                s[idx] = s[idx] * sc
                       + __builtin_amdgcn_exp2f(fmaf(v0, SCALE2, -mn))
                       + __builtin_amdgcn_exp2f(fmaf(v1, SCALE2, -mn))
                       + __builtin_amdgcn_exp2f(fmaf(v2, SCALE2, -mn))
                       + __builtin_amdgcn_exp2f(fmaf(v3, SCALE2, -mn));
                m2[idx] = mn;
            }
        }
    }

    // Cross-lane merge: 64 partials per row (16 ln x 4 waves), LDS overlay.
    __syncthreads();                       // all A reads done; reuse ldsA
    float* smf = (float*)ldsA;             // [64][64] m partials (16 KB)
    float* ssf = smf + TM * 64;            // [64][64] s partials (16 KB)
    const int p = w * 16 + ln;
#pragma unroll
    for (int ti = 0; ti < 4; ++ti)
#pragma unroll
        for (int r = 0; r < 4; ++r) {
            const int rl = ti * 16 + quad * 4 + r;
            smf[rl * 64 + p] = m2[ti * 4 + r];
            ssf[rl * 64 + p] = s[ti * 4 + r];
        }
    __syncthreads();
    if (tid < TM) {
        float M = -INFINITY;
#pragma unroll
        for (int x = 0; x < 64; ++x) M = fmaxf(M, smf[tid * 64 + x]);
        float S = 0.0f;
#pragma unroll
        for (int x = 0; x < 64; ++x)
            S += ssf[tid * 64 + x] * __builtin_amdgcn_exp2f(smf[tid * 64 + x] - M);
        part_m[(size_t)(rowBase + tid) * NSLICE + slice] = M;
        part_s[(size_t)(rowBase + tid) * NSLICE + slice] = S;
    }
}

// Kernel P: pos[i] = dot(z[i], z[i+1]) / T in exact fp32, one wave per row.
__global__ __launch_bounds__(256) void pos_kernel(
    const float* __restrict__ z, float* __restrict__ pos)
{
    const int wave = (blockIdx.x * blockDim.x + threadIdx.x) >> 6;
    const int lane = threadIdx.x & 63;
    if (wave >= NROWS - 1) return;
    const float4 av = *(const float4*)(z + (size_t)wave * DIM + lane * 4);
    const float4 bv = *(const float4*)(z + (size_t)(wave + 1) * DIM + lane * 4);
    float sum = av.x * bv.x + av.y * bv.y + av.z * bv.z + av.w * bv.w;
#pragma unroll
    for (int off = 32; off > 0; off >>= 1) sum += __shfl_down(sum, off);
    if (lane == 0) pos[wave] = sum * INV_T;
}

// Kernel F: combine slice partials (base-2) -> lse (natural log) -> loss.
__global__ __launch_bounds__(256) void final_kernel(
    const float* __restrict__ part_m, const float* __restrict__ part_s,
    const float* __restrict__ pos, float* __restrict__ out)
{
    __shared__ float red[256];
    const int tid = threadIdx.x;
    float local = 0.0f;
    for (int i = tid; i < NROWS - 1; i += 256) {
        if ((i & 255) == 255) continue;   // t == L-1: no positive pair
        const float* pm = part_m + (size_t)i * NSLICE;
        const float* ps = part_s + (size_t)i * NSLICE;
        float M = -INFINITY;
#pragma unroll
        for (int x = 0; x < NSLICE; ++x) M = fmaxf(M, pm[x]);
        float S = 0.0f;
#pragma unroll
        for (int x = 0; x < NSLICE; ++x)
            S += ps[x] * __builtin_amdgcn_exp2f(pm[x] - M);
        const float lse = LN2 * (M + __builtin_amdgcn_logf(S));  // v_log = log2
        local += lse - pos[i];
    }
    red[tid] = local;
    __syncthreads();
    for (int st = 128; st > 0; st >>= 1) {
        if (tid < st) red[tid] += red[tid + st];
        __syncthreads();
    }
    if (tid == 0) out[0] = red[0] / 4080.0f;   // B*(L-1) valid pairs
}

extern "C" void kernel_launch(void* const* d_in, const int* in_sizes, int n_in,
                              void* d_out, int out_size, void* d_ws, size_t ws_size,
                              hipStream_t stream) {
    const float* z   = (const float*)d_in[0];   // [4096, 256]
    // d_in[1] = va_values: dead code in the reference, unused.
    const float* mem = (const float*)d_in[2];   // [16384, 256]

    // ws layout: cand bf16 [20480*256] | part_m f32 [4096*16]
    //          | part_s f32 [4096*16] | pos f32 [4096]
    ushort_t* cand = (ushort_t*)d_ws;
    float* part_m  = (float*)(cand + (size_t)NCAND * DIM);
    float* part_s  = part_m + (size_t)NROWS * NSLICE;
    float* pos     = part_s + (size_t)NROWS * NSLICE;

    const int castBlocks = NCAND * DIM / 4 / 256;   // 5120
    cast_kernel<<<dim3(castBlocks), dim3(256), 0, stream>>>(z, mem, cand);
    mfma_lse_kernel<<<dim3(NROWS / TM, NSLICE), dim3(256), 0, stream>>>(
        cand, cand, part_m, part_s);   // zb = first NROWS rows of cand
    pos_kernel<<<dim3((NROWS + 3) / 4), dim3(256), 0, stream>>>(z, pos);
    final_kernel<<<dim3(1), dim3(256), 0, stream>>>(part_m, part_s, pos, (float*)d_out);
}

// Round 4
// 177.820 us; speedup vs baseline: 1.0949x; 1.0949x over previous
//
#include <hip/hip_runtime.h>
#include <hip/hip_bf16.h>
#include <math.h>

// Problem constants (B=16, L=256, D=256, K=16384)
#define NROWS 4096               // B*L anchors / z rows
#define KMEM  16384
#define NCAND 20480              // NROWS + KMEM candidates
#define DIM   256                // feature dim
#define TM    128                // anchor rows per block
#define TN    128                // candidate cols per tile
#define BK    64                 // k-depth per LDS stage (bf16)
#define NSLICE 24                // 768 blocks = exactly 3 blocks/CU
// 160 col-tiles of 128: slices 0..15 get 7 tiles, 16..23 get 6 (16*7+8*6=160)
#define INV_T  (1.0f / 0.07f)
#define SCALE2 (1.4426950408889634f / 0.07f)  // log2(e)/T
#define LN2    0.6931471805599453f
#define MERGE_STRIDE 33          // conflict-free merge reads: (tid*33+x)%32 distinct

typedef short  short8 __attribute__((ext_vector_type(8)));  // 8 bf16 (4 VGPRs)
typedef float  f32x4  __attribute__((ext_vector_type(4)));  // MFMA C/D
typedef unsigned short ushort_t;

// RNE float->bf16 (inputs are finite normals; no NaN path needed)
__device__ inline ushort_t f2bf(float x) {
    union { float f; unsigned u; } a; a.f = x;
    unsigned r = a.u + 0x7fff + ((a.u >> 16) & 1);
    return (ushort_t)(r >> 16);
}

// async global->LDS, 16B per lane, dest = wave-uniform base + lane*16
__device__ inline void load_lds16(const void* g, void* l) {
    __builtin_amdgcn_global_load_lds(
        (const __attribute__((address_space(1))) unsigned int*)g,
        (__attribute__((address_space(3))) unsigned int*)l, 16, 0, 0);
}

// Kernel 0: cast fp32 -> bf16 into cand = [z ; mem]; also zero the loss
// accumulator + completion counter (runs before final_kernel in stream order).
__global__ __launch_bounds__(256) void cast_kernel(
    const float* __restrict__ z, const float* __restrict__ mem,
    ushort_t* __restrict__ cand, float* __restrict__ acc_ct)
{
    if (blockIdx.x == 0 && threadIdx.x == 0) {
        acc_ct[0] = 0.0f;                      // loss accumulator
        ((unsigned*)acc_ct)[1] = 0u;           // arrival counter
    }
    const int idx = blockIdx.x * 256 + threadIdx.x;  // float4 index, < 1310720
    const int ZQ = NROWS * DIM / 4;                  // 262144
    const float4 v = (idx < ZQ) ? ((const float4*)z)[idx]
                                : ((const float4*)mem)[idx - ZQ];
    ushort4 u; u.x = f2bf(v.x); u.y = f2bf(v.y); u.z = f2bf(v.z); u.w = f2bf(v.w);
    ((ushort4*)cand)[idx] = u;
}

// Kernel A: MFMA flash-LSE (R2 structure). Block = 4 waves (2x2), 128 rows x
// a slice of 6-7 128-col tiles. Per tile: K-loop stages A/B (128xBK bf16)
// into LDS via global_load_lds w=16 with XOR chunk swizzle, 16x16x32 bf16
// MFMA into 4x4 f32x4 acc, per-lane online (m,s) in base-2. Merge uses
// stride-33 LDS overlay (conflict-free).
__global__ __launch_bounds__(256) void mfma_lse_kernel(
    const ushort_t* __restrict__ cand,
    float* __restrict__ part_m, float* __restrict__ part_s)
{
    __shared__ __align__(16) char smem_raw[2 * TM * MERGE_STRIDE * 4];  // 33792 >= 32768 staging
    ushort_t* ldsA = (ushort_t*)smem_raw;        // [128][BK] bf16, chunk-swizzled
    ushort_t* ldsB = ldsA + TM * BK;             // [128][BK]

    const int tid  = threadIdx.x;
    const int lane = tid & 63;
    const int w    = tid >> 6;        // wave 0..3
    const int wr   = w >> 1;          // wave row half (0/1)
    const int wc   = w & 1;           // wave col half
    const int quad = lane >> 4;
    const int ln   = lane & 15;
    const int rowBase = blockIdx.x * TM;
    const int slice   = blockIdx.y;   // 0..23
    const int tstart  = slice * 6 + min(slice, 16);
    const int ntile   = (slice < 16) ? 7 : 6;

    // Per-lane online-softmax state for the 16 rows this lane owns in C-layout
    float m2[16], s[16];
#pragma unroll
    for (int i = 0; i < 16; ++i) { m2[i] = -INFINITY; s[i] = 0.0f; }

    for (int t = 0; t < ntile; ++t) {
        const int colBase = (tstart + t) * TN;
        f32x4 acc[4][4];
#pragma unroll
        for (int ti = 0; ti < 4; ++ti)
#pragma unroll
            for (int tj = 0; tj < 4; ++tj) acc[ti][tj] = (f32x4)0.0f;

        for (int kk = 0; kk < DIM; kk += BK) {
            __syncthreads();   // previous stage's LDS reads complete
            // Stage: wave w covers tile rows [w*32, w*32+32). Lane l -> row
            // +l/8, LDS chunk l%8, global chunk c = (l%8) ^ (row&7).
#pragma unroll
            for (int u = 0; u < 4; ++u) {
                const int r  = w * 32 + u * 8 + (lane >> 3);
                const int c  = (lane & 7) ^ (r & 7);
                load_lds16(cand + (size_t)(rowBase + r) * DIM + kk + c * 8,
                           ldsA + (w * 32 + u * 8) * BK);
                load_lds16(cand + (size_t)(colBase + r) * DIM + kk + c * 8,
                           ldsB + (w * 32 + u * 8) * BK);
            }
            __syncthreads();   // drains vmcnt (global_load_lds) before reads

            // 2 k-steps of 32 depth; A-frag: lane holds A[m=ln][k=quad*8+j]
#pragma unroll
            for (int ks = 0; ks < 2; ++ks) {
                short8 af[4], bfr[4];
#pragma unroll
                for (int ti = 0; ti < 4; ++ti) {
                    const int row = wr * 64 + ti * 16 + ln;
                    const int p = row * 8 + ((ks * 4 + quad) ^ (row & 7));
                    af[ti] = *(const short8*)(ldsA + p * 8);
                }
#pragma unroll
                for (int tj = 0; tj < 4; ++tj) {
                    const int col = wc * 64 + tj * 16 + ln;
                    const int p = col * 8 + ((ks * 4 + quad) ^ (col & 7));
                    bfr[tj] = *(const short8*)(ldsB + p * 8);
                }
#pragma unroll
                for (int ti = 0; ti < 4; ++ti)
#pragma unroll
                    for (int tj = 0; tj < 4; ++tj)
                        acc[ti][tj] = __builtin_amdgcn_mfma_f32_16x16x32_bf16(
                            af[ti], bfr[tj], acc[ti][tj], 0, 0, 0);
            }
        }

        // Epilogue: base-2 online update (scale folded via fma). Per-lane only.
        // C/D layout: col = ln (+16*tj +64*wc), row = quad*4+reg (+16*ti +64*wr)
        const bool hasDiag = (colBase < rowBase + TM) && (rowBase < colBase + TN);
#pragma unroll
        for (int ti = 0; ti < 4; ++ti) {
#pragma unroll
            for (int r = 0; r < 4; ++r) {
                const int idx = ti * 4 + r;
                float v0 = acc[ti][0][r], v1 = acc[ti][1][r];
                float v2 = acc[ti][2][r], v3 = acc[ti][3][r];
                if (hasDiag) {
                    const int grow = rowBase + wr * 64 + ti * 16 + quad * 4 + r;
                    const int gc0  = colBase + wc * 64 + ln;
                    if (gc0      == grow) v0 = -3.0e38f;   // mask self-sim
                    if (gc0 + 16 == grow) v1 = -3.0e38f;
                    if (gc0 + 32 == grow) v2 = -3.0e38f;
                    if (gc0 + 48 == grow) v3 = -3.0e38f;
                }
                const float tmax = fmaxf(fmaxf(v0, v1), fmaxf(v2, v3)) * SCALE2;
                const float mo = m2[idx];
                const float mn = fmaxf(mo, tmax);
                const float sc = __builtin_amdgcn_exp2f(mo - mn);  // exp2(-inf)=0
                s[idx] = s[idx] * sc
                       + __builtin_amdgcn_exp2f(fmaf(v0, SCALE2, -mn))
                       + __builtin_amdgcn_exp2f(fmaf(v1, SCALE2, -mn))
                       + __builtin_amdgcn_exp2f(fmaf(v2, SCALE2, -mn))
                       + __builtin_amdgcn_exp2f(fmaf(v3, SCALE2, -mn));
                m2[idx] = mn;
            }
        }
    }

    // Cross-lane merge: 32 partials per row (16 ln x 2 wc), stride-33 overlay
    // so the per-row reads hit 32 distinct banks ((tid*33+x)%32 = (tid+x)%32).
    __syncthreads();                       // all tile reads done; reuse smem
    float* smf = (float*)smem_raw;         // [128][33] m partials
    float* ssf = smf + TM * MERGE_STRIDE;  // [128][33] s partials
    const int p = wc * 16 + ln;
#pragma unroll
    for (int ti = 0; ti < 4; ++ti)
#pragma unroll
        for (int r = 0; r < 4; ++r) {
            const int rl = wr * 64 + ti * 16 + quad * 4 + r;
            smf[rl * MERGE_STRIDE + p] = m2[ti * 4 + r];
            ssf[rl * MERGE_STRIDE + p] = s[ti * 4 + r];
        }
    __syncthreads();
    if (tid < TM) {
        float M = -INFINITY;
#pragma unroll
        for (int x = 0; x < 32; ++x) M = fmaxf(M, smf[tid * MERGE_STRIDE + x]);
        float S = 0.0f;
#pragma unroll
        for (int x = 0; x < 32; ++x)
            S += ssf[tid * MERGE_STRIDE + x]
               * __builtin_amdgcn_exp2f(smf[tid * MERGE_STRIDE + x] - M);
        part_m[(size_t)(rowBase + tid) * NSLICE + slice] = M;
        part_s[(size_t)(rowBase + tid) * NSLICE + slice] = S;
    }
}

// Kernel F: fused pos-dot + slice combine + loss reduce. 16 blocks x 256
// threads, one thread per row. Last-arriving block writes the scalar.
__global__ __launch_bounds__(256) void final_kernel(
    const float* __restrict__ z,
    const float* __restrict__ part_m, const float* __restrict__ part_s,
    float* __restrict__ acc_ct, float* __restrict__ out)
{
    __shared__ float red[256];
    const int tid = threadIdx.x;
    const int i = blockIdx.x * 256 + tid;   // row 0..4095
    float local = 0.0f;
    if ((i & 255) != 255) {                 // valid pair (also guards i=4095)
        const float* pm = part_m + (size_t)i * NSLICE;
        const float* ps = part_s + (size_t)i * NSLICE;
        float M = -INFINITY;
#pragma unroll
        for (int x = 0; x < NSLICE; ++x) M = fmaxf(M, pm[x]);
        float S = 0.0f;
#pragma unroll
        for (int x = 0; x < NSLICE; ++x)
            S += ps[x] * __builtin_amdgcn_exp2f(pm[x] - M);
        const float lse = LN2 * (M + __builtin_amdgcn_logf(S));  // v_log = log2
        // positive similarity: exact fp32 dot(z[i], z[i+1]) / T
        const float4* a = (const float4*)(z + (size_t)i * DIM);
        const float4* b = (const float4*)(z + (size_t)(i + 1) * DIM);
        float dot = 0.0f;
#pragma unroll
        for (int q = 0; q < DIM / 4; ++q) {
            const float4 av = a[q], bv = b[q];
            dot += av.x * bv.x + av.y * bv.y + av.z * bv.z + av.w * bv.w;
        }
        local = lse - dot * INV_T;
    }
    red[tid] = local;
    __syncthreads();
    for (int st = 128; st > 0; st >>= 1) {
        if (tid < st) red[tid] += red[tid + st];
        __syncthreads();
    }
    if (tid == 0) {
        atomicAdd(&acc_ct[0], red[0]);      // device-scope float atomic
        __threadfence();
        const unsigned old = atomicAdd((unsigned*)&acc_ct[1], 1u);
        if (old == gridDim.x - 1) {
            const float total = atomicAdd(&acc_ct[0], 0.0f);  // coherent read
            out[0] = total / 4080.0f;       // B*(L-1) valid pairs
        }
    }
}

extern "C" void kernel_launch(void* const* d_in, const int* in_sizes, int n_in,
                              void* d_out, int out_size, void* d_ws, size_t ws_size,
                              hipStream_t stream) {
    const float* z   = (const float*)d_in[0];   // [4096, 256]
    // d_in[1] = va_values: dead code in the reference, unused.
    const float* mem = (const float*)d_in[2];   // [16384, 256]

    // ws layout: cand bf16 [20480*256] | part_m f32 [4096*24]
    //          | part_s f32 [4096*24] | acc_ct f32[2]
    ushort_t* cand = (ushort_t*)d_ws;
    float* part_m  = (float*)(cand + (size_t)NCAND * DIM);
    float* part_s  = part_m + (size_t)NROWS * NSLICE;
    float* acc_ct  = part_s + (size_t)NROWS * NSLICE;

    const int castBlocks = NCAND * DIM / 4 / 256;   // 5120
    cast_kernel<<<dim3(castBlocks), dim3(256), 0, stream>>>(z, mem, cand, acc_ct);
    mfma_lse_kernel<<<dim3(NROWS / TM, NSLICE), dim3(256), 0, stream>>>(
        cand, part_m, part_s);
    final_kernel<<<dim3(NROWS / 256), dim3(256), 0, stream>>>(
        z, part_m, part_s, acc_ct, (float*)d_out);
}

// Round 5
// 139.389 us; speedup vs baseline: 1.3968x; 1.2757x over previous
//
#include <hip/hip_runtime.h>
#include <hip/hip_bf16.h>
#include <math.h>

// Problem constants (B=16, L=256, D=256, K=16384)
#define NROWS 4096               // B*L anchors / z rows
#define KMEM  16384
#define NCAND 20480              // NROWS + KMEM candidates
#define DIM   256                // feature dim
#define TM    128                // anchor rows per block
#define TN    128                // candidate cols per tile
#define BK    64                 // k-depth per LDS stage (bf16)
#define NSLICE 16                // 512 blocks = exactly 2 blocks/CU (64KB LDS)
#define COLS_PER_SLICE (NCAND / NSLICE)       // 1280
#define TILES_PER_SLICE (COLS_PER_SLICE / TN) // 10, uniform
#define INV_T  (1.0f / 0.07f)
#define SCALE2 (1.4426950408889634f / 0.07f)  // log2(e)/T
#define LN2    0.6931471805599453f
#define MERGE_STRIDE 33          // conflict-free merge: (tid*33+x)%32 distinct

typedef short  short8 __attribute__((ext_vector_type(8)));  // 8 bf16 (4 VGPRs)
typedef float  f32x4  __attribute__((ext_vector_type(4)));  // MFMA C/D
typedef unsigned short ushort_t;

// RNE float->bf16 (inputs are finite normals; no NaN path needed)
__device__ inline ushort_t f2bf(float x) {
    union { float f; unsigned u; } a; a.f = x;
    unsigned r = a.u + 0x7fff + ((a.u >> 16) & 1);
    return (ushort_t)(r >> 16);
}

// async global->LDS, 16B per lane, dest = wave-uniform base + lane*16
__device__ inline void load_lds16(const void* g, void* l) {
    __builtin_amdgcn_global_load_lds(
        (const __attribute__((address_space(1))) unsigned int*)g,
        (__attribute__((address_space(3))) unsigned int*)l, 16, 0, 0);
}

// Kernel 0: cast fp32 -> bf16 into cand = [z ; mem]; zero loss accumulator.
__global__ __launch_bounds__(256) void cast_kernel(
    const float* __restrict__ z, const float* __restrict__ mem,
    ushort_t* __restrict__ cand, float* __restrict__ acc_ct)
{
    if (blockIdx.x == 0 && threadIdx.x == 0) {
        acc_ct[0] = 0.0f;                      // loss accumulator
        ((unsigned*)acc_ct)[1] = 0u;           // arrival counter
    }
    const int idx = blockIdx.x * 256 + threadIdx.x;  // float4 index, < 1310720
    const int ZQ = NROWS * DIM / 4;                  // 262144
    const float4 v = (idx < ZQ) ? ((const float4*)z)[idx]
                                : ((const float4*)mem)[idx - ZQ];
    ushort4 u; u.x = f2bf(v.x); u.y = f2bf(v.y); u.z = f2bf(v.z); u.w = f2bf(v.w);
    ((ushort4*)cand)[idx] = u;
}

// Kernel A: double-buffered MFMA flash-LSE. 40-stage software pipeline:
// at each BK=64 stage, FIRST issue next stage's global_load_lds into the
// other buffer, THEN run this stage's 32 MFMAs, THEN one __syncthreads().
// The barrier's vmcnt drain is covered by ~620 cyc of MFMA instead of being
// fully exposed (the R2/R4 structure's stall). Prefetch crosses tile
// boundaries; per-tile softmax epilogue runs while next tile's loads fly.
__global__ __launch_bounds__(256) void mfma_lse_kernel(
    const ushort_t* __restrict__ cand,
    float* __restrict__ part_m, float* __restrict__ part_s)
{
    __shared__ __align__(16) char smem_raw[65536];       // 2x(A 16KB + B 16KB)
    ushort_t* ldsA = (ushort_t*)smem_raw;                // [2][128*64]
    ushort_t* ldsB = ldsA + 2 * TM * BK;                 // [2][128*64]

    const int tid  = threadIdx.x;
    const int lane = tid & 63;
    const int w    = tid >> 6;        // wave 0..3
    const int wr   = w >> 1;          // wave row half (0/1)
    const int wc   = w & 1;           // wave col half
    const int quad = lane >> 4;
    const int ln   = lane & 15;
    const int rowBase = blockIdx.x * TM;
    const int slice   = blockIdx.y;
    const int colSliceBase = slice * COLS_PER_SLICE;

    // Staging geometry (loop-invariant): wave w covers tile rows
    // [w*32, w*32+32), lane l -> row srow + u*8, chunk c = (l&7)^(srow&7)
    // (invariant across u since u*8 = 0 mod 8). XOR swizzle keeps fragment
    // ds_read_b128 conflict-free (proven: 197K conflicts in R4).
    const int srow = w * 32 + (lane >> 3);
    const int sc   = (lane & 7) ^ (srow & 7);
    const ushort_t* agp    = cand + (size_t)(rowBase + srow) * DIM + sc * 8;
    const ushort_t* bgbase = cand + (size_t)(colSliceBase + srow) * DIM + sc * 8;
    ushort_t* lab = ldsA + (w * 32) * BK;   // + buf*TM*BK + u*8*BK
    ushort_t* lbb = ldsB + (w * 32) * BK;

    // issue one stage's 8 async loads (tile t, k-offset kk, buffer buf)
    auto stage = [&](int t, int kk, int buf) {
        const ushort_t* ag = agp + kk;
        const ushort_t* bg = bgbase + t * (TN * DIM) + kk;
        ushort_t* la = lab + buf * (TM * BK);
        ushort_t* lb = lbb + buf * (TM * BK);
#pragma unroll
        for (int u = 0; u < 4; ++u) {
            load_lds16(ag + u * 8 * DIM, la + u * 8 * BK);
            load_lds16(bg + u * 8 * DIM, lb + u * 8 * BK);
        }
    };

    float m2[16], s[16];
#pragma unroll
    for (int i = 0; i < 16; ++i) { m2[i] = -INFINITY; s[i] = 0.0f; }

    f32x4 acc[4][4];
#pragma unroll
    for (int ti = 0; ti < 4; ++ti)
#pragma unroll
        for (int tj = 0; tj < 4; ++tj) acc[ti][tj] = (f32x4)0.0f;

    stage(0, 0, 0);        // prologue: stage 0 -> buffer 0
    __syncthreads();

    for (int t = 0; t < TILES_PER_SLICE; ++t) {
#pragma unroll
        for (int q = 0; q < 4; ++q) {
            const int buf = q & 1;          // s = 4t+q -> buf = s&1 = q&1
            // prefetch next stage into the other buffer (in flight across
            // this stage's compute; drained by the barrier below)
            if (q < 3)                       stage(t,     (q + 1) * BK, buf ^ 1);
            else if (t + 1 < TILES_PER_SLICE) stage(t + 1, 0,           buf ^ 1);

            // compute stage s from buffer buf: 2 k-steps x 16 MFMA
            const ushort_t* la = ldsA + buf * (TM * BK);
            const ushort_t* lb = ldsB + buf * (TM * BK);
#pragma unroll
            for (int ks = 0; ks < 2; ++ks) {
                short8 af[4], bfr[4];
#pragma unroll
                for (int ti = 0; ti < 4; ++ti) {
                    const int row = wr * 64 + ti * 16 + ln;
                    const int p = row * 8 + ((ks * 4 + quad) ^ (row & 7));
                    af[ti] = *(const short8*)(la + p * 8);
                }
#pragma unroll
                for (int tj = 0; tj < 4; ++tj) {
                    const int col = wc * 64 + tj * 16 + ln;
                    const int p = col * 8 + ((ks * 4 + quad) ^ (col & 7));
                    bfr[tj] = *(const short8*)(lb + p * 8);
                }
#pragma unroll
                for (int ti = 0; ti < 4; ++ti)
#pragma unroll
                    for (int tj = 0; tj < 4; ++tj)
                        acc[ti][tj] = __builtin_amdgcn_mfma_f32_16x16x32_bf16(
                            af[ti], bfr[tj], acc[ti][tj], 0, 0, 0);
            }

            if (q == 3) {
                // Epilogue for tile t (runs while tile t+1's loads fly).
                // C/D layout: col = ln+16*tj+64*wc, row = quad*4+reg+16*ti+64*wr
                const int colBase = colSliceBase + t * TN;
                const bool hasDiag =
                    (colBase < rowBase + TM) && (rowBase < colBase + TN);
#pragma unroll
                for (int ti = 0; ti < 4; ++ti) {
#pragma unroll
                    for (int r = 0; r < 4; ++r) {
                        const int idx = ti * 4 + r;
                        float v0 = acc[ti][0][r], v1 = acc[ti][1][r];
                        float v2 = acc[ti][2][r], v3 = acc[ti][3][r];
                        if (hasDiag) {
                            const int grow = rowBase + wr * 64 + ti * 16 + quad * 4 + r;
                            const int gc0  = colBase + wc * 64 + ln;
                            if (gc0      == grow) v0 = -3.0e38f;  // mask self
                            if (gc0 + 16 == grow) v1 = -3.0e38f;
                            if (gc0 + 32 == grow) v2 = -3.0e38f;
                            if (gc0 + 48 == grow) v3 = -3.0e38f;
                        }
                        const float tmax = fmaxf(fmaxf(v0, v1), fmaxf(v2, v3)) * SCALE2;
                        const float mo = m2[idx];
                        const float mn = fmaxf(mo, tmax);
                        const float sc2 = __builtin_amdgcn_exp2f(mo - mn);
                        s[idx] = s[idx] * sc2
                               + __builtin_amdgcn_exp2f(fmaf(v0, SCALE2, -mn))
                               + __builtin_amdgcn_exp2f(fmaf(v1, SCALE2, -mn))
                               + __builtin_amdgcn_exp2f(fmaf(v2, SCALE2, -mn))
                               + __builtin_amdgcn_exp2f(fmaf(v3, SCALE2, -mn));
                        m2[idx] = mn;
                        acc[ti][0][r] = 0.0f; acc[ti][1][r] = 0.0f;
                        acc[ti][2][r] = 0.0f; acc[ti][3][r] = 0.0f;
                    }
                }
            }
            __syncthreads();   // publishes prefetched stage; frees old buffer
        }
    }

    // Cross-lane merge: 32 partials per row (16 ln x 2 wc), stride-33 overlay
    // (conflict-free: (tid*33+x)%32 = (tid+x)%32). Loop barrier above already
    // separated the last compute from this smem reuse.
    float* smf = (float*)smem_raw;         // [128][33] m partials
    float* ssf = smf + TM * MERGE_STRIDE;  // [128][33] s partials
    const int p = wc * 16 + ln;
#pragma unroll
    for (int ti = 0; ti < 4; ++ti)
#pragma unroll
        for (int r = 0; r < 4; ++r) {
            const int rl = wr * 64 + ti * 16 + quad * 4 + r;
            smf[rl * MERGE_STRIDE + p] = m2[ti * 4 + r];
            ssf[rl * MERGE_STRIDE + p] = s[ti * 4 + r];
        }
    __syncthreads();
    if (tid < TM) {
        float M = -INFINITY;
#pragma unroll
        for (int x = 0; x < 32; ++x) M = fmaxf(M, smf[tid * MERGE_STRIDE + x]);
        float S = 0.0f;
#pragma unroll
        for (int x = 0; x < 32; ++x)
            S += ssf[tid * MERGE_STRIDE + x]
               * __builtin_amdgcn_exp2f(smf[tid * MERGE_STRIDE + x] - M);
        part_m[(size_t)(rowBase + tid) * NSLICE + slice] = M;
        part_s[(size_t)(rowBase + tid) * NSLICE + slice] = S;
    }
}

// Kernel F: fused pos-dot + slice combine + loss reduce. 16 blocks x 256
// threads, one thread per row. Last-arriving block writes the scalar.
__global__ __launch_bounds__(256) void final_kernel(
    const float* __restrict__ z,
    const float* __restrict__ part_m, const float* __restrict__ part_s,
    float* __restrict__ acc_ct, float* __restrict__ out)
{
    __shared__ float red[256];
    const int tid = threadIdx.x;
    const int i = blockIdx.x * 256 + tid;   // row 0..4095
    float local = 0.0f;
    if ((i & 255) != 255) {                 // valid pair (also guards i=4095)
        const float* pm = part_m + (size_t)i * NSLICE;
        const float* ps = part_s + (size_t)i * NSLICE;
        float M = -INFINITY;
#pragma unroll
        for (int x = 0; x < NSLICE; ++x) M = fmaxf(M, pm[x]);
        float S = 0.0f;
#pragma unroll
        for (int x = 0; x < NSLICE; ++x)
            S += ps[x] * __builtin_amdgcn_exp2f(pm[x] - M);
        const float lse = LN2 * (M + __builtin_amdgcn_logf(S));  // v_log = log2
        // positive similarity: exact fp32 dot(z[i], z[i+1]) / T
        const float4* a = (const float4*)(z + (size_t)i * DIM);
        const float4* b = (const float4*)(z + (size_t)(i + 1) * DIM);
        float dot = 0.0f;
#pragma unroll
        for (int q = 0; q < DIM / 4; ++q) {
            const float4 av = a[q], bv = b[q];
            dot += av.x * bv.x + av.y * bv.y + av.z * bv.z + av.w * bv.w;
        }
        local = lse - dot * INV_T;
    }
    red[tid] = local;
    __syncthreads();
    for (int st = 128; st > 0; st >>= 1) {
        if (tid < st) red[tid] += red[tid + st];
        __syncthreads();
    }
    if (tid == 0) {
        atomicAdd(&acc_ct[0], red[0]);      // device-scope float atomic
        __threadfence();
        const unsigned old = atomicAdd((unsigned*)&acc_ct[1], 1u);
        if (old == gridDim.x - 1) {
            const float total = atomicAdd(&acc_ct[0], 0.0f);  // coherent read
            out[0] = total / 4080.0f;       // B*(L-1) valid pairs
        }
    }
}

extern "C" void kernel_launch(void* const* d_in, const int* in_sizes, int n_in,
                              void* d_out, int out_size, void* d_ws, size_t ws_size,
                              hipStream_t stream) {
    const float* z   = (const float*)d_in[0];   // [4096, 256]
    // d_in[1] = va_values: dead code in the reference, unused.
    const float* mem = (const float*)d_in[2];   // [16384, 256]

    // ws layout: cand bf16 [20480*256] | part_m f32 [4096*16]
    //          | part_s f32 [4096*16] | acc_ct f32[2]
    ushort_t* cand = (ushort_t*)d_ws;
    float* part_m  = (float*)(cand + (size_t)NCAND * DIM);
    float* part_s  = part_m + (size_t)NROWS * NSLICE;
    float* acc_ct  = part_s + (size_t)NROWS * NSLICE;

    const int castBlocks = NCAND * DIM / 4 / 256;   // 5120
    cast_kernel<<<dim3(castBlocks), dim3(256), 0, stream>>>(z, mem, cand, acc_ct);
    mfma_lse_kernel<<<dim3(NROWS / TM, NSLICE), dim3(256), 0, stream>>>(
        cand, part_m, part_s);
    final_kernel<<<dim3(NROWS / 256), dim3(256), 0, stream>>>(
        z, part_m, part_s, acc_ct, (float*)d_out);
}